// Round 21
// baseline (70.124 us; speedup 1.0000x reference)
//
#include <hip/hip_runtime.h>

typedef __bf16 bf16;
typedef __attribute__((ext_vector_type(8))) __bf16 bf16x8;
typedef __attribute__((ext_vector_type(4))) __bf16 bf16x4;
typedef __attribute__((ext_vector_type(4))) float  f32x4;

#define MFMA16(A,B,C) __builtin_amdgcn_mfma_f32_16x16x32_bf16(A,B,C,0,0,0)
// Force a fragment to be materialized in arch VGPRs at this point.
#define PIN(v8) asm volatile("" : "+v"(*(f32x4*)&(v8)))

// problem constants
constexpr int ROWS = 262144;
constexpr int DIN  = 38;
constexpr int H1N  = 256;
constexpr int H2N  = 256;
constexpr int PN   = 128;
constexpr int WROWS = 32;  // rows per wave (2 mtiles)
constexpr int SHP  = 528;  // LDS row stride (512B data + 16B pad, bank-uniform)

// ws layout (bytes)
constexpr int W1P_OFF = 0;        // 16nt*2ks*64lanes*16B = 32768
constexpr int W2P_OFF = 32768;    // 16*8*64*16 = 131072
constexpr int VP_OFF  = 163840;   // 8*64*16 = 8192
constexpr int C_OFF   = 172032;   // 6 floats

// ---------------------------------------------------------------------------
// Prep (blockIdx-branched, wave-uniform): W1 pack, W2 pack, V fold, c scalars
// ---------------------------------------------------------------------------
__global__ void prep_kernel(const float* __restrict__ W1,
                            const float* __restrict__ W2,
                            const float* __restrict__ W3,
                            const float* __restrict__ b3,
                            const float* __restrict__ lw_i, const float* __restrict__ bew_i,
                            const float* __restrict__ lw_e, const float* __restrict__ bew_e,
                            const float* __restrict__ lw_m, const float* __restrict__ bew_m,
                            unsigned char* __restrict__ ws)
{
    const int b   = blockIdx.x;
    const int tid = threadIdx.x;

    if (b < 8) {                         // ---- W1 pack ----
        const int u = b * 256 + tid;
        const int lane = u & 63, ks = (u >> 6) & 1, nt = u >> 7;
        const int n  = nt * 16 + (lane & 15);
        const int kb = ks * 32 + (lane >> 4) * 8;
        bf16x8 v;
        #pragma unroll
        for (int i = 0; i < 8; ++i) {
            const int k = kb + i;
            v[i] = (bf16)(k < DIN ? W1[n * DIN + k] : 0.f);
        }
        ((bf16x8*)(ws + W1P_OFF))[u] = v;
    } else if (b < 40) {                 // ---- W2 pack ----
        const int u = (b - 8) * 256 + tid;
        const int lane = u & 63, ks = (u >> 6) & 7, nt = u >> 9;
        const int n  = nt * 16 + (lane & 15);
        const int kb = ks * 32 + (lane >> 4) * 8;
        const float4 v0 = *(const float4*)(W2 + n * H1N + kb);
        const float4 v1 = *(const float4*)(W2 + n * H1N + kb + 4);
        bf16x8 v;
        v[0] = (bf16)v0.x; v[1] = (bf16)v0.y; v[2] = (bf16)v0.z; v[3] = (bf16)v0.w;
        v[4] = (bf16)v1.x; v[5] = (bf16)v1.y; v[6] = (bf16)v1.z; v[7] = (bf16)v1.w;
        ((bf16x8*)(ws + W2P_OFF))[u] = v;
    } else if (b == 40) {                // ---- V fold ----
        __shared__ float wv[6][PN];
        const float* __restrict__ srcs[6] = {lw_i, bew_i, lw_e, bew_e, lw_m, bew_m};
        if (tid < PN) {
            #pragma unroll
            for (int h = 0; h < 6; ++h) wv[h][tid] = srcs[h][tid];
        }
        __syncthreads();
        const int k = tid;
        float s[6] = {0.f, 0.f, 0.f, 0.f, 0.f, 0.f};
        #pragma unroll 4
        for (int p = 0; p < PN; ++p) {
            const float w3 = W3[p * H2N + k];
            #pragma unroll
            for (int h = 0; h < 6; ++h) s[h] += wv[h][p] * w3;
        }
        const int ks = k >> 5, lq = (k >> 3) & 3, i = k & 7;
        unsigned char* vp = ws + VP_OFF;
        #pragma unroll
        for (int h = 0; h < 6; ++h)
            *(bf16*)(vp + (ks * 64 + lq * 16 + h) * 16 + i * 2) = (bf16)s[h];
        #pragma unroll
        for (int h = 6; h < 16; ++h)
            *(bf16*)(vp + (ks * 64 + lq * 16 + h) * 16 + i * 2) = (bf16)0.f;
    } else {                             // ---- c scalars ----
        __shared__ float red[6][PN];
        const float* __restrict__ srcs[6] = {lw_i, bew_i, lw_e, bew_e, lw_m, bew_m};
        if (tid < PN) {
            const float bv = b3[tid];
            #pragma unroll
            for (int h = 0; h < 6; ++h) red[h][tid] = bv * srcs[h][tid];
        }
        __syncthreads();
        if (tid < 6) {
            float s = 0.f;
            for (int p = 0; p < PN; ++p) s += red[tid][p];
            ((float*)(ws + C_OFF))[tid] = s;
        }
    }
}

// ---------------------------------------------------------------------------
// R16 + L2 weight stream restructured as a 4-slot ring of 4-frag batches
// (same 64-reg budget as wA[8]/wB[8], but prefetch DISTANCE = 3 batches
// ≈ 234 cyc of MFMA cover vs 156 before — covering the ~200-400cyc L2
// latency). No PIN in L2: the waitcnt must land at consumption (3 clusters
// after issue), which the compiler's counted vmcnt does natively. L1, head,
// epilogue identical to R16. Zero barriers; 2 blocks/CU, 8 waves/CU.
// ---------------------------------------------------------------------------
__global__ __launch_bounds__(256, 2)
void fused_kernel(const float* __restrict__ X,
                  const float* __restrict__ b1,
                  const float* __restrict__ b2,
                  const unsigned char* __restrict__ ws,
                  const float* __restrict__ lb_i, const float* __restrict__ beb_i,
                  const float* __restrict__ bw_i, const float* __restrict__ bb_i,
                  const float* __restrict__ lb_e, const float* __restrict__ beb_e,
                  const float* __restrict__ bw_e, const float* __restrict__ bb_e,
                  const float* __restrict__ lb_m, const float* __restrict__ beb_m,
                  const float* __restrict__ bw_m, const float* __restrict__ bb_m,
                  float* __restrict__ out)
{
    __shared__ __attribute__((aligned(16))) unsigned char sH[4][WROWS * SHP]; // 67.6 KB

    const int tid  = threadIdx.x;
    const int lane = tid & 63;
    const int wid  = tid >> 6;
    const int lr   = lane & 15;
    const int lq   = lane >> 4;
    unsigned char* const myH = sH[wid];
    const int rowbase = (blockIdx.x * 4 + wid) * WROWS;

    const bf16x8* __restrict__ W1p = (const bf16x8*)(ws + W1P_OFF);
    const bf16x8* __restrict__ W2p = (const bf16x8*)(ws + W2P_OFF);
    const bf16x8* __restrict__ Vp  = (const bf16x8*)(ws + VP_OFF);
    const float*  __restrict__ cvec = (const float*)(ws + C_OFF);

    // ---- epilogue X scalars (issued early, consumed last) ----
    float ep0[2] = {0.f, 0.f}, ep7[2] = {0.f, 0.f};
    float ep9[2] = {0.f, 0.f}, ep12[2] = {0.f, 0.f};
    if (lq == 0) {
        #pragma unroll
        for (int mt = 0; mt < 2; ++mt) {
            const float* xr = X + (size_t)(rowbase + mt * 16 + lr) * DIN;
            ep0[mt] = xr[0]; ep7[mt] = xr[7]; ep9[mt] = xr[9]; ep12[mt] = xr[12];
        }
    }

    // ---- X fragments direct from global ----
    bf16x8 xf[2][2];   // [mt][ks]
    #pragma unroll
    for (int mt = 0; mt < 2; ++mt) {
        const float* xr = X + (size_t)(rowbase + mt * 16 + lr) * DIN;
        const float2 a0 = *(const float2*)(xr + lq * 8 + 0);
        const float2 a1 = *(const float2*)(xr + lq * 8 + 2);
        const float2 a2 = *(const float2*)(xr + lq * 8 + 4);
        const float2 a3 = *(const float2*)(xr + lq * 8 + 6);
        bf16x8 v0;
        v0[0] = (bf16)a0.x; v0[1] = (bf16)a0.y; v0[2] = (bf16)a1.x; v0[3] = (bf16)a1.y;
        v0[4] = (bf16)a2.x; v0[5] = (bf16)a2.y; v0[6] = (bf16)a3.x; v0[7] = (bf16)a3.y;
        xf[mt][0] = v0;
        bf16x8 v1;
        #pragma unroll
        for (int i = 0; i < 8; ++i) v1[i] = (bf16)0.f;
        if (lq == 0) {
            const float2 c0 = *(const float2*)(xr + 32);
            const float2 c1 = *(const float2*)(xr + 34);
            const float2 c2 = *(const float2*)(xr + 36);
            v1[0] = (bf16)c0.x; v1[1] = (bf16)c0.y; v1[2] = (bf16)c1.x;
            v1[3] = (bf16)c1.y; v1[4] = (bf16)c2.x; v1[5] = (bf16)c2.y;
        }
        xf[mt][1] = v1;
    }

    // ---- layer 1: pair-pipelined + PIN (unchanged from R16) ----
    {
        bf16x8 f0 = W1p[0 * 64 + lane];
        bf16x8 f1 = W1p[1 * 64 + lane];
        bf16x8 f2 = W1p[2 * 64 + lane];
        bf16x8 f3 = W1p[3 * 64 + lane];
        #pragma unroll
        for (int pr = 0; pr < 8; ++pr) {
            bf16x8 g0, g1, g2, g3;
            if (pr < 7) {
                g0 = W1p[((pr + 1) * 4 + 0) * 64 + lane];
                g1 = W1p[((pr + 1) * 4 + 1) * 64 + lane];
                g2 = W1p[((pr + 1) * 4 + 2) * 64 + lane];
                g3 = W1p[((pr + 1) * 4 + 3) * 64 + lane];
            }
            const int j0 = pr * 2, j1 = pr * 2 + 1;
            {
                const float4 bb = *(const float4*)(b1 + j0 * 16 + lq * 4);
                const float ba[4] = {bb.x, bb.y, bb.z, bb.w};
                f32x4 a0 = (f32x4){0.f, 0.f, 0.f, 0.f};
                f32x4 a1 = (f32x4){0.f, 0.f, 0.f, 0.f};
                __builtin_amdgcn_s_setprio(1);
                a0 = MFMA16(f0, xf[0][0], a0); a0 = MFMA16(f1, xf[0][1], a0);
                a1 = MFMA16(f0, xf[1][0], a1); a1 = MFMA16(f1, xf[1][1], a1);
                __builtin_amdgcn_s_setprio(0);
                bf16x4 h0, h1v;
                #pragma unroll
                for (int r2 = 0; r2 < 4; ++r2) {
                    h0[r2]  = (bf16)fmaxf(a0[r2] + ba[r2], 0.f);
                    h1v[r2] = (bf16)fmaxf(a1[r2] + ba[r2], 0.f);
                }
                const int coff = (j0 * 16 + lq * 4) * 2;
                *(bf16x4*)(myH + lr * SHP + coff)        = h0;
                *(bf16x4*)(myH + (16 + lr) * SHP + coff) = h1v;
            }
            {
                const float4 bb = *(const float4*)(b1 + j1 * 16 + lq * 4);
                const float ba[4] = {bb.x, bb.y, bb.z, bb.w};
                f32x4 a0 = (f32x4){0.f, 0.f, 0.f, 0.f};
                f32x4 a1 = (f32x4){0.f, 0.f, 0.f, 0.f};
                __builtin_amdgcn_s_setprio(1);
                a0 = MFMA16(f2, xf[0][0], a0); a0 = MFMA16(f3, xf[0][1], a0);
                a1 = MFMA16(f2, xf[1][0], a1); a1 = MFMA16(f3, xf[1][1], a1);
                __builtin_amdgcn_s_setprio(0);
                if (pr < 7) { PIN(g0); PIN(g1); PIN(g2); PIN(g3); }
                bf16x4 h0, h1v;
                #pragma unroll
                for (int r2 = 0; r2 < 4; ++r2) {
                    h0[r2]  = (bf16)fmaxf(a0[r2] + ba[r2], 0.f);
                    h1v[r2] = (bf16)fmaxf(a1[r2] + ba[r2], 0.f);
                }
                const int coff = (j1 * 16 + lq * 4) * 2;
                *(bf16x4*)(myH + lr * SHP + coff)        = h0;
                *(bf16x4*)(myH + (16 + lr) * SHP + coff) = h1v;
            }
            f0 = g0; f1 = g1; f2 = g2; f3 = g3;
        }
    }

    // ---- h1 fragments -> registers (64 VGPR) ----
    bf16x8 hf[2][8];
    #pragma unroll
    for (int ks = 0; ks < 8; ++ks) {
        hf[0][ks] = *(const bf16x8*)(myH + lr * SHP        + ks * 64 + lq * 16);
        hf[1][ks] = *(const bf16x8*)(myH + (16 + lr) * SHP + ks * 64 + lq * 16);
    }

    // ---- layer 2: 4-deep x 4-frag ring-pipelined weight stream ----
    // batch b (0..31): j = b>>1, k-half = b&1; issue batch b+3 before
    // consuming batch b -> waitcnt for a batch lands ~3 clusters after its
    // issue (counted vmcnt; newer batches stay in flight).
    {
        bf16x8 ring[4][4];
        #pragma unroll
        for (int b = 0; b < 3; ++b)
            #pragma unroll
            for (int q = 0; q < 4; ++q)
                ring[b][q] = W2p[(((b >> 1) * 8) + (b & 1) * 4 + q) * 64 + lane];

        f32x4 a0 = (f32x4){0.f, 0.f, 0.f, 0.f};
        f32x4 a1 = (f32x4){0.f, 0.f, 0.f, 0.f};
        #pragma unroll
        for (int b = 0; b < 32; ++b) {
            const int j  = b >> 1;
            const int kb = (b & 1) * 4;
            if ((b & 1) == 0) {
                a0 = (f32x4){0.f, 0.f, 0.f, 0.f};
                a1 = (f32x4){0.f, 0.f, 0.f, 0.f};
            }
            if (b + 3 < 32) {
                const int nb = b + 3;
                #pragma unroll
                for (int q = 0; q < 4; ++q)
                    ring[nb & 3][q] = W2p[(((nb >> 1) * 8) + (nb & 1) * 4 + q) * 64 + lane];
            }
            __builtin_amdgcn_s_setprio(1);
            #pragma unroll
            for (int q = 0; q < 4; ++q) {
                a0 = MFMA16(ring[b & 3][q], hf[0][kb + q], a0);
                a1 = MFMA16(ring[b & 3][q], hf[1][kb + q], a1);
            }
            __builtin_amdgcn_s_setprio(0);
            if (b & 1) {
                const float4 bb = *(const float4*)(b2 + j * 16 + lq * 4);
                const float ba[4] = {bb.x, bb.y, bb.z, bb.w};
                bf16x4 h0, h1v;
                #pragma unroll
                for (int r2 = 0; r2 < 4; ++r2) {
                    h0[r2]  = (bf16)fmaxf(a0[r2] + ba[r2], 0.f);
                    h1v[r2] = (bf16)fmaxf(a1[r2] + ba[r2], 0.f);
                }
                const int coff = (j * 16 + lq * 4) * 2;
                *(bf16x4*)(myH + lr * SHP + coff)        = h0;
                *(bf16x4*)(myH + (16 + lr) * SHP + coff) = h1v;
            }
        }
    }

    // ---- folded layer3 + heads ----
    {
        bf16x8 vf[8];
        #pragma unroll
        for (int ks = 0; ks < 8; ++ks) vf[ks] = Vp[ks * 64 + lane];
        f32x4 acc[2] = {(f32x4){0.f, 0.f, 0.f, 0.f}, (f32x4){0.f, 0.f, 0.f, 0.f}};
        #pragma unroll
        for (int ks = 0; ks < 8; ++ks) {
            const bf16x8 h0  = *(const bf16x8*)(myH + lr * SHP        + ks * 64 + lq * 16);
            const bf16x8 h1v = *(const bf16x8*)(myH + (16 + lr) * SHP + ks * 64 + lq * 16);
            acc[0] = MFMA16(vf[ks], h0,  acc[0]);
            acc[1] = MFMA16(vf[ks], h1v, acc[1]);
        }
        const float hlb[3]  = {lb_i[0],  lb_e[0],  lb_m[0]};
        const float hbeb[3] = {beb_i[0], beb_e[0], beb_m[0]};
        const float hbw[3]  = {bw_i[0],  bw_e[0],  bw_m[0]};
        const float hbb[3]  = {bb_i[0],  bb_e[0],  bb_m[0]};
        #pragma unroll
        for (int mt = 0; mt < 2; ++mt) {
            const float d4 = __shfl(acc[mt][0], lane + 16);
            const float d5 = __shfl(acc[mt][1], lane + 16);
            if (lq == 0) {
                const float dots[6] = {acc[mt][0], acc[mt][1], acc[mt][2], acc[mt][3], d4, d5};
                const float xres[3] = {ep7[mt], ep9[mt], ep12[mt]};
                const int row = rowbase + mt * 16 + lr;
                #pragma unroll
                for (int h = 0; h < 3; ++h) {
                    const float lin = dots[2 * h] + cvec[2 * h] + hlb[h];
                    const float e   = (dots[2 * h + 1] + cvec[2 * h + 1]) * ep0[mt] + hbeb[h];
                    const float y   = hbw[h] * e * lin + hbb[h] + xres[h];
                    out[(size_t)row * 3 + h] = y;
                }
            }
        }
    }
}

extern "C" void kernel_launch(void* const* d_in, const int* in_sizes, int n_in,
                              void* d_out, int out_size, void* d_ws, size_t ws_size,
                              hipStream_t stream) {
    const float* X   = (const float*)d_in[0];
    const float* W1  = (const float*)d_in[1];
    const float* b1  = (const float*)d_in[2];
    const float* W2  = (const float*)d_in[3];
    const float* b2  = (const float*)d_in[4];
    const float* W3  = (const float*)d_in[5];
    const float* b3  = (const float*)d_in[6];
    const float* lw_i  = (const float*)d_in[7];
    const float* lb_i  = (const float*)d_in[8];
    const float* bew_i = (const float*)d_in[9];
    const float* beb_i = (const float*)d_in[10];
    const float* bw_i  = (const float*)d_in[11];
    const float* bb_i  = (const float*)d_in[12];
    const float* lw_e  = (const float*)d_in[13];
    const float* lb_e  = (const float*)d_in[14];
    const float* bew_e = (const float*)d_in[15];
    const float* beb_e = (const float*)d_in[16];
    const float* bw_e  = (const float*)d_in[17];
    const float* bb_e  = (const float*)d_in[18];
    const float* lw_m  = (const float*)d_in[19];
    const float* lb_m  = (const float*)d_in[20];
    const float* bew_m = (const float*)d_in[21];
    const float* beb_m = (const float*)d_in[22];
    const float* bw_m  = (const float*)d_in[23];
    const float* bb_m  = (const float*)d_in[24];

    unsigned char* ws = (unsigned char*)d_ws;
    float* outp = (float*)d_out;

    prep_kernel<<<42, 256, 0, stream>>>(W1, W2, W3, b3,
                                        lw_i, bew_i, lw_e, bew_e, lw_m, bew_m, ws);

    // 2048 blocks x 4 independent waves x 32 rows, no barriers
    fused_kernel<<<ROWS / (4 * WROWS), 256, 0, stream>>>(X, b1, b2, ws,
                                                         lb_i, beb_i, bw_i, bb_i,
                                                         lb_e, beb_e, bw_e, bb_e,
                                                         lb_m, beb_m, bw_m, bb_m,
                                                         outp);
}

// Round 22
// 68.815 us; speedup vs baseline: 1.0190x; 1.0190x over previous
//
#include <hip/hip_runtime.h>

typedef __bf16 bf16;
typedef __attribute__((ext_vector_type(8))) __bf16 bf16x8;
typedef __attribute__((ext_vector_type(4))) __bf16 bf16x4;
typedef __attribute__((ext_vector_type(4))) float  f32x4;

#define MFMA16(A,B,C) __builtin_amdgcn_mfma_f32_16x16x32_bf16(A,B,C,0,0,0)
// Force a fragment to be materialized in arch VGPRs at this point.
#define PIN(v8) asm volatile("" : "+v"(*(f32x4*)&(v8)))

// problem constants
constexpr int ROWS = 262144;
constexpr int DIN  = 38;
constexpr int H1N  = 256;
constexpr int H2N  = 256;
constexpr int PN   = 128;
constexpr int WROWS = 32;  // rows per wave (2 mtiles)
constexpr int SHP  = 528;  // LDS row stride (512B data + 16B pad, bank-uniform)

// ws layout (bytes)
constexpr int W1P_OFF = 0;        // 16nt*2ks*64lanes*16B = 32768
constexpr int W2P_OFF = 32768;    // 16*8*64*16 = 131072
constexpr int VP_OFF  = 163840;   // 8*64*16 = 8192
constexpr int C_OFF   = 172032;   // 6 floats

// ---------------------------------------------------------------------------
// Prep (blockIdx-branched, wave-uniform): W1 pack, W2 pack, V fold, c scalars
// ---------------------------------------------------------------------------
__global__ void prep_kernel(const float* __restrict__ W1,
                            const float* __restrict__ W2,
                            const float* __restrict__ W3,
                            const float* __restrict__ b3,
                            const float* __restrict__ lw_i, const float* __restrict__ bew_i,
                            const float* __restrict__ lw_e, const float* __restrict__ bew_e,
                            const float* __restrict__ lw_m, const float* __restrict__ bew_m,
                            unsigned char* __restrict__ ws)
{
    const int b   = blockIdx.x;
    const int tid = threadIdx.x;

    if (b < 8) {                         // ---- W1 pack ----
        const int u = b * 256 + tid;
        const int lane = u & 63, ks = (u >> 6) & 1, nt = u >> 7;
        const int n  = nt * 16 + (lane & 15);
        const int kb = ks * 32 + (lane >> 4) * 8;
        bf16x8 v;
        #pragma unroll
        for (int i = 0; i < 8; ++i) {
            const int k = kb + i;
            v[i] = (bf16)(k < DIN ? W1[n * DIN + k] : 0.f);
        }
        ((bf16x8*)(ws + W1P_OFF))[u] = v;
    } else if (b < 40) {                 // ---- W2 pack ----
        const int u = (b - 8) * 256 + tid;
        const int lane = u & 63, ks = (u >> 6) & 7, nt = u >> 9;
        const int n  = nt * 16 + (lane & 15);
        const int kb = ks * 32 + (lane >> 4) * 8;
        const float4 v0 = *(const float4*)(W2 + n * H1N + kb);
        const float4 v1 = *(const float4*)(W2 + n * H1N + kb + 4);
        bf16x8 v;
        v[0] = (bf16)v0.x; v[1] = (bf16)v0.y; v[2] = (bf16)v0.z; v[3] = (bf16)v0.w;
        v[4] = (bf16)v1.x; v[5] = (bf16)v1.y; v[6] = (bf16)v1.z; v[7] = (bf16)v1.w;
        ((bf16x8*)(ws + W2P_OFF))[u] = v;
    } else if (b == 40) {                // ---- V fold ----
        __shared__ float wv[6][PN];
        const float* __restrict__ srcs[6] = {lw_i, bew_i, lw_e, bew_e, lw_m, bew_m};
        if (tid < PN) {
            #pragma unroll
            for (int h = 0; h < 6; ++h) wv[h][tid] = srcs[h][tid];
        }
        __syncthreads();
        const int k = tid;
        float s[6] = {0.f, 0.f, 0.f, 0.f, 0.f, 0.f};
        #pragma unroll 4
        for (int p = 0; p < PN; ++p) {
            const float w3 = W3[p * H2N + k];
            #pragma unroll
            for (int h = 0; h < 6; ++h) s[h] += wv[h][p] * w3;
        }
        const int ks = k >> 5, lq = (k >> 3) & 3, i = k & 7;
        unsigned char* vp = ws + VP_OFF;
        #pragma unroll
        for (int h = 0; h < 6; ++h)
            *(bf16*)(vp + (ks * 64 + lq * 16 + h) * 16 + i * 2) = (bf16)s[h];
        #pragma unroll
        for (int h = 6; h < 16; ++h)
            *(bf16*)(vp + (ks * 64 + lq * 16 + h) * 16 + i * 2) = (bf16)0.f;
    } else {                             // ---- c scalars ----
        __shared__ float red[6][PN];
        const float* __restrict__ srcs[6] = {lw_i, bew_i, lw_e, bew_e, lw_m, bew_m};
        if (tid < PN) {
            const float bv = b3[tid];
            #pragma unroll
            for (int h = 0; h < 6; ++h) red[h][tid] = bv * srcs[h][tid];
        }
        __syncthreads();
        if (tid < 6) {
            float s = 0.f;
            for (int p = 0; p < PN; ++p) s += red[tid][p];
            ((float*)(ws + C_OFF))[tid] = s;
        }
    }
}

// ---------------------------------------------------------------------------
// FINAL KERNEL (R16 structure, best measured 68.9us).
// Each wave owns 32 rows, ZERO barriers, per-wave private LDS slab.
// L2 j-loop: wA/wB named prefetch — next pair's 8 frags issued BEFORE the
// current pair's MFMA cluster, PINned right AFTER it (waitcnt lands under
// ~155cyc of MFMA cover). Same for L1's g0..g3. s_setprio(1) around MFMA
// clusters. LDS 67.6 KB -> 2 blocks/CU, 8 waves/CU, 2 waves/SIMD with full
// operand residency — the measured optimum of the occupancy-residency space:
//   {1 w/SIMD: 112us} {2 w/SIMD + residency: 68.9} {3 w: 75 spill}
//   {4 w, operands evicted: 96}.  Plateau set by the ~130-VGPR no-spill
//   ceiling; MFMA floor ~22us, remainder is unhideable operand latency.
// ---------------------------------------------------------------------------
__global__ __launch_bounds__(256, 2)
void fused_kernel(const float* __restrict__ X,
                  const float* __restrict__ b1,
                  const float* __restrict__ b2,
                  const unsigned char* __restrict__ ws,
                  const float* __restrict__ lb_i, const float* __restrict__ beb_i,
                  const float* __restrict__ bw_i, const float* __restrict__ bb_i,
                  const float* __restrict__ lb_e, const float* __restrict__ beb_e,
                  const float* __restrict__ bw_e, const float* __restrict__ bb_e,
                  const float* __restrict__ lb_m, const float* __restrict__ beb_m,
                  const float* __restrict__ bw_m, const float* __restrict__ bb_m,
                  float* __restrict__ out)
{
    __shared__ __attribute__((aligned(16))) unsigned char sH[4][WROWS * SHP]; // 67.6 KB

    const int tid  = threadIdx.x;
    const int lane = tid & 63;
    const int wid  = tid >> 6;
    const int lr   = lane & 15;
    const int lq   = lane >> 4;
    unsigned char* const myH = sH[wid];
    const int rowbase = (blockIdx.x * 4 + wid) * WROWS;

    const bf16x8* __restrict__ W1p = (const bf16x8*)(ws + W1P_OFF);
    const bf16x8* __restrict__ W2p = (const bf16x8*)(ws + W2P_OFF);
    const bf16x8* __restrict__ Vp  = (const bf16x8*)(ws + VP_OFF);
    const float*  __restrict__ cvec = (const float*)(ws + C_OFF);

    // ---- epilogue X scalars (issued early, consumed last) ----
    float ep0[2] = {0.f, 0.f}, ep7[2] = {0.f, 0.f};
    float ep9[2] = {0.f, 0.f}, ep12[2] = {0.f, 0.f};
    if (lq == 0) {
        #pragma unroll
        for (int mt = 0; mt < 2; ++mt) {
            const float* xr = X + (size_t)(rowbase + mt * 16 + lr) * DIN;
            ep0[mt] = xr[0]; ep7[mt] = xr[7]; ep9[mt] = xr[9]; ep12[mt] = xr[12];
        }
    }

    // ---- X fragments direct from global ----
    bf16x8 xf[2][2];   // [mt][ks]
    #pragma unroll
    for (int mt = 0; mt < 2; ++mt) {
        const float* xr = X + (size_t)(rowbase + mt * 16 + lr) * DIN;
        const float2 a0 = *(const float2*)(xr + lq * 8 + 0);
        const float2 a1 = *(const float2*)(xr + lq * 8 + 2);
        const float2 a2 = *(const float2*)(xr + lq * 8 + 4);
        const float2 a3 = *(const float2*)(xr + lq * 8 + 6);
        bf16x8 v0;
        v0[0] = (bf16)a0.x; v0[1] = (bf16)a0.y; v0[2] = (bf16)a1.x; v0[3] = (bf16)a1.y;
        v0[4] = (bf16)a2.x; v0[5] = (bf16)a2.y; v0[6] = (bf16)a3.x; v0[7] = (bf16)a3.y;
        xf[mt][0] = v0;
        bf16x8 v1;
        #pragma unroll
        for (int i = 0; i < 8; ++i) v1[i] = (bf16)0.f;
        if (lq == 0) {
            const float2 c0 = *(const float2*)(xr + 32);
            const float2 c1 = *(const float2*)(xr + 34);
            const float2 c2 = *(const float2*)(xr + 36);
            v1[0] = (bf16)c0.x; v1[1] = (bf16)c0.y; v1[2] = (bf16)c1.x;
            v1[3] = (bf16)c1.y; v1[4] = (bf16)c2.x; v1[5] = (bf16)c2.y;
        }
        xf[mt][1] = v1;
    }

    // ---- layer 1: pair-pipelined + PIN (prefetch next pair's 4 frags) ----
    {
        bf16x8 f0 = W1p[0 * 64 + lane];
        bf16x8 f1 = W1p[1 * 64 + lane];
        bf16x8 f2 = W1p[2 * 64 + lane];
        bf16x8 f3 = W1p[3 * 64 + lane];
        #pragma unroll
        for (int pr = 0; pr < 8; ++pr) {
            bf16x8 g0, g1, g2, g3;
            if (pr < 7) {
                g0 = W1p[((pr + 1) * 4 + 0) * 64 + lane];
                g1 = W1p[((pr + 1) * 4 + 1) * 64 + lane];
                g2 = W1p[((pr + 1) * 4 + 2) * 64 + lane];
                g3 = W1p[((pr + 1) * 4 + 3) * 64 + lane];
            }
            const int j0 = pr * 2, j1 = pr * 2 + 1;
            {
                const float4 bb = *(const float4*)(b1 + j0 * 16 + lq * 4);
                const float ba[4] = {bb.x, bb.y, bb.z, bb.w};
                f32x4 a0 = (f32x4){0.f, 0.f, 0.f, 0.f};
                f32x4 a1 = (f32x4){0.f, 0.f, 0.f, 0.f};
                __builtin_amdgcn_s_setprio(1);
                a0 = MFMA16(f0, xf[0][0], a0); a0 = MFMA16(f1, xf[0][1], a0);
                a1 = MFMA16(f0, xf[1][0], a1); a1 = MFMA16(f1, xf[1][1], a1);
                __builtin_amdgcn_s_setprio(0);
                bf16x4 h0, h1v;
                #pragma unroll
                for (int r2 = 0; r2 < 4; ++r2) {
                    h0[r2]  = (bf16)fmaxf(a0[r2] + ba[r2], 0.f);
                    h1v[r2] = (bf16)fmaxf(a1[r2] + ba[r2], 0.f);
                }
                const int coff = (j0 * 16 + lq * 4) * 2;
                *(bf16x4*)(myH + lr * SHP + coff)        = h0;
                *(bf16x4*)(myH + (16 + lr) * SHP + coff) = h1v;
            }
            {
                const float4 bb = *(const float4*)(b1 + j1 * 16 + lq * 4);
                const float ba[4] = {bb.x, bb.y, bb.z, bb.w};
                f32x4 a0 = (f32x4){0.f, 0.f, 0.f, 0.f};
                f32x4 a1 = (f32x4){0.f, 0.f, 0.f, 0.f};
                __builtin_amdgcn_s_setprio(1);
                a0 = MFMA16(f2, xf[0][0], a0); a0 = MFMA16(f3, xf[0][1], a0);
                a1 = MFMA16(f2, xf[1][0], a1); a1 = MFMA16(f3, xf[1][1], a1);
                __builtin_amdgcn_s_setprio(0);
                if (pr < 7) { PIN(g0); PIN(g1); PIN(g2); PIN(g3); }
                bf16x4 h0, h1v;
                #pragma unroll
                for (int r2 = 0; r2 < 4; ++r2) {
                    h0[r2]  = (bf16)fmaxf(a0[r2] + ba[r2], 0.f);
                    h1v[r2] = (bf16)fmaxf(a1[r2] + ba[r2], 0.f);
                }
                const int coff = (j1 * 16 + lq * 4) * 2;
                *(bf16x4*)(myH + lr * SHP + coff)        = h0;
                *(bf16x4*)(myH + (16 + lr) * SHP + coff) = h1v;
            }
            f0 = g0; f1 = g1; f2 = g2; f3 = g3;
        }
    }

    // ---- h1 fragments -> registers (64 VGPR) ----
    bf16x8 hf[2][8];
    #pragma unroll
    for (int ks = 0; ks < 8; ++ks) {
        hf[0][ks] = *(const bf16x8*)(myH + lr * SHP        + ks * 64 + lq * 16);
        hf[1][ks] = *(const bf16x8*)(myH + (16 + lr) * SHP + ks * 64 + lq * 16);
    }

    // ---- layer 2: pair-pipelined weight stream + PIN ----
    {
        bf16x8 wA[8], wB[8];
        #pragma unroll
        for (int ks = 0; ks < 8; ++ks) wA[ks] = W2p[ks * 64 + lane];
        #pragma unroll
        for (int jp = 0; jp < 8; ++jp) {
            const int j0 = jp * 2, j1 = jp * 2 + 1;
            #pragma unroll
            for (int ks = 0; ks < 8; ++ks) wB[ks] = W2p[(j1 * 8 + ks) * 64 + lane];
            {
                f32x4 a0 = (f32x4){0.f, 0.f, 0.f, 0.f};
                f32x4 a1 = (f32x4){0.f, 0.f, 0.f, 0.f};
                __builtin_amdgcn_s_setprio(1);
                #pragma unroll
                for (int ks = 0; ks < 8; ++ks) {
                    a0 = MFMA16(wA[ks], hf[0][ks], a0);
                    a1 = MFMA16(wA[ks], hf[1][ks], a1);
                }
                __builtin_amdgcn_s_setprio(0);
                // wB must be materialized by now — waitcnt lands here, under
                // the MFMA cover, not inside the next cluster.
                #pragma unroll
                for (int ks = 0; ks < 8; ++ks) PIN(wB[ks]);
                const float4 bb = *(const float4*)(b2 + j0 * 16 + lq * 4);
                const float ba[4] = {bb.x, bb.y, bb.z, bb.w};
                bf16x4 h0, h1v;
                #pragma unroll
                for (int r2 = 0; r2 < 4; ++r2) {
                    h0[r2]  = (bf16)fmaxf(a0[r2] + ba[r2], 0.f);
                    h1v[r2] = (bf16)fmaxf(a1[r2] + ba[r2], 0.f);
                }
                const int coff = (j0 * 16 + lq * 4) * 2;
                *(bf16x4*)(myH + lr * SHP + coff)        = h0;
                *(bf16x4*)(myH + (16 + lr) * SHP + coff) = h1v;
            }
            if (jp < 7) {
                #pragma unroll
                for (int ks = 0; ks < 8; ++ks) wA[ks] = W2p[((j1 + 1) * 8 + ks) * 64 + lane];
            }
            {
                f32x4 a0 = (f32x4){0.f, 0.f, 0.f, 0.f};
                f32x4 a1 = (f32x4){0.f, 0.f, 0.f, 0.f};
                __builtin_amdgcn_s_setprio(1);
                #pragma unroll
                for (int ks = 0; ks < 8; ++ks) {
                    a0 = MFMA16(wB[ks], hf[0][ks], a0);
                    a1 = MFMA16(wB[ks], hf[1][ks], a1);
                }
                __builtin_amdgcn_s_setprio(0);
                if (jp < 7) {
                    #pragma unroll
                    for (int ks = 0; ks < 8; ++ks) PIN(wA[ks]);
                }
                const float4 bb = *(const float4*)(b2 + j1 * 16 + lq * 4);
                const float ba[4] = {bb.x, bb.y, bb.z, bb.w};
                bf16x4 h0, h1v;
                #pragma unroll
                for (int r2 = 0; r2 < 4; ++r2) {
                    h0[r2]  = (bf16)fmaxf(a0[r2] + ba[r2], 0.f);
                    h1v[r2] = (bf16)fmaxf(a1[r2] + ba[r2], 0.f);
                }
                const int coff = (j1 * 16 + lq * 4) * 2;
                *(bf16x4*)(myH + lr * SHP + coff)        = h0;
                *(bf16x4*)(myH + (16 + lr) * SHP + coff) = h1v;
            }
        }
    }

    // ---- folded layer3 + heads ----
    {
        bf16x8 vf[8];
        #pragma unroll
        for (int ks = 0; ks < 8; ++ks) vf[ks] = Vp[ks * 64 + lane];
        f32x4 acc[2] = {(f32x4){0.f, 0.f, 0.f, 0.f}, (f32x4){0.f, 0.f, 0.f, 0.f}};
        #pragma unroll
        for (int ks = 0; ks < 8; ++ks) {
            const bf16x8 h0  = *(const bf16x8*)(myH + lr * SHP        + ks * 64 + lq * 16);
            const bf16x8 h1v = *(const bf16x8*)(myH + (16 + lr) * SHP + ks * 64 + lq * 16);
            acc[0] = MFMA16(vf[ks], h0,  acc[0]);
            acc[1] = MFMA16(vf[ks], h1v, acc[1]);
        }
        const float hlb[3]  = {lb_i[0],  lb_e[0],  lb_m[0]};
        const float hbeb[3] = {beb_i[0], beb_e[0], beb_m[0]};
        const float hbw[3]  = {bw_i[0],  bw_e[0],  bw_m[0]};
        const float hbb[3]  = {bb_i[0],  bb_e[0],  bb_m[0]};
        #pragma unroll
        for (int mt = 0; mt < 2; ++mt) {
            const float d4 = __shfl(acc[mt][0], lane + 16);
            const float d5 = __shfl(acc[mt][1], lane + 16);
            if (lq == 0) {
                const float dots[6] = {acc[mt][0], acc[mt][1], acc[mt][2], acc[mt][3], d4, d5};
                const float xres[3] = {ep7[mt], ep9[mt], ep12[mt]};
                const int row = rowbase + mt * 16 + lr;
                #pragma unroll
                for (int h = 0; h < 3; ++h) {
                    const float lin = dots[2 * h] + cvec[2 * h] + hlb[h];
                    const float e   = (dots[2 * h + 1] + cvec[2 * h + 1]) * ep0[mt] + hbeb[h];
                    const float y   = hbw[h] * e * lin + hbb[h] + xres[h];
                    out[(size_t)row * 3 + h] = y;
                }
            }
        }
    }
}

extern "C" void kernel_launch(void* const* d_in, const int* in_sizes, int n_in,
                              void* d_out, int out_size, void* d_ws, size_t ws_size,
                              hipStream_t stream) {
    const float* X   = (const float*)d_in[0];
    const float* W1  = (const float*)d_in[1];
    const float* b1  = (const float*)d_in[2];
    const float* W2  = (const float*)d_in[3];
    const float* b2  = (const float*)d_in[4];
    const float* W3  = (const float*)d_in[5];
    const float* b3  = (const float*)d_in[6];
    const float* lw_i  = (const float*)d_in[7];
    const float* lb_i  = (const float*)d_in[8];
    const float* bew_i = (const float*)d_in[9];
    const float* beb_i = (const float*)d_in[10];
    const float* bw_i  = (const float*)d_in[11];
    const float* bb_i  = (const float*)d_in[12];
    const float* lw_e  = (const float*)d_in[13];
    const float* lb_e  = (const float*)d_in[14];
    const float* bew_e = (const float*)d_in[15];
    const float* beb_e = (const float*)d_in[16];
    const float* bw_e  = (const float*)d_in[17];
    const float* bb_e  = (const float*)d_in[18];
    const float* lw_m  = (const float*)d_in[19];
    const float* lb_m  = (const float*)d_in[20];
    const float* bew_m = (const float*)d_in[21];
    const float* beb_m = (const float*)d_in[22];
    const float* bw_m  = (const float*)d_in[23];
    const float* bb_m  = (const float*)d_in[24];

    unsigned char* ws = (unsigned char*)d_ws;
    float* outp = (float*)d_out;

    prep_kernel<<<42, 256, 0, stream>>>(W1, W2, W3, b3,
                                        lw_i, bew_i, lw_e, bew_e, lw_m, bew_m, ws);

    // 2048 blocks x 4 independent waves x 32 rows, no barriers
    fused_kernel<<<ROWS / (4 * WROWS), 256, 0, stream>>>(X, b1, b2, ws,
                                                         lb_i, beb_i, bw_i, bb_i,
                                                         lb_e, beb_e, bw_e, bb_e,
                                                         lb_m, beb_m, bw_m, bb_m,
                                                         outp);
}